// Round 13
// baseline (150.789 us; speedup 1.0000x reference)
//
#include <hip/hip_runtime.h>
#include <hip/hip_bf16.h>

#define C_DIM 512
#define L_DIM 1024
#define KK 64
#define KG 65
#define KP 80   // padded k rows (5 tiles of 16)

using f32x4  = __attribute__((ext_vector_type(4))) float;
using bf16x8 = __attribute__((ext_vector_type(8))) short;

union U4 { uint4 u; bf16x8 b; };

__device__ __forceinline__ unsigned bfh(float x) { return __float_as_uint(x) >> 16; }
__device__ __forceinline__ float bfh_f(float x) { return __uint_as_float(__float_as_uint(x) & 0xFFFF0000u); }

// pack two fp32 -> word of 2 bf16 (truncation): low16 = a, high16 = b
__device__ __forceinline__ unsigned pack2(float a, float b) {
    return __builtin_amdgcn_perm(__float_as_uint(b), __float_as_uint(a), 0x07060302u);
}

// ---------------- prep: split conv_w into bf16 hi/lo, pad to 80 rows ----------------
__global__ void k_prep(const float* __restrict__ conv_w, const float* __restrict__ conv_b,
                       unsigned short* __restrict__ wtH, unsigned short* __restrict__ wtL,
                       float* __restrict__ wb)
{
    int k = blockIdx.x;           // 0..79
    int t = threadIdx.x;          // 0..255, 2 c's each
    for (int j = 0; j < 2; ++j) {
        int c = t * 2 + j;
        float v = (k < KG) ? conv_w[k * C_DIM + c] : 0.f;
        unsigned h = bfh(v);
        float r = v - __uint_as_float(h << 16);
        wtH[k * C_DIM + c] = (unsigned short)h;
        wtL[k * C_DIM + c] = (unsigned short)bfh(r);
    }
    if (t == 0) wb[k] = (k < KG) ? conv_b[k] : -1e30f;
}

// ---------------- Stage 1: c-split wave pairs, lean registers ----------------
// Grid (16 lb, 64 n), block 512 = 8 waves = 4 l-groups x 2 c-halves.
// Wave (lg, chalf) computes partial logits for 16 l over its 256-c half:
// per-l instruction mix identical to the 32l/wave kernel, but 8192 waves
// (8/SIMD) instead of 2048 for latency hiding. One scalar-layout LDS combine
// (stride-1, conflict-free) + one barrier at the end; chalf=1 waves retire.
__global__ __launch_bounds__(512, 4) void k_s1(
    const float* __restrict__ x, const unsigned short* __restrict__ wtH,
    const unsigned short* __restrict__ wtL, const float* __restrict__ wb,
    unsigned short* __restrict__ aPh, unsigned short* __restrict__ aPl,
    float* __restrict__ asum_part)
{
    __shared__ float accbuf[4][5][4][68];   // [lg][kt][reg][lane] scalar, ~21.8 KB
    __shared__ float ssbuf[4][64];          // 1 KB

    const int lb = blockIdx.x, n = blockIdx.y;
    const int t = threadIdx.x, lane = t & 63, w = t >> 6;
    const int lg = w & 3, chalf = w >> 2;
    const int arow = lane & 15;          // A/C row & B col within tile (= l offset)
    const int agrp = lane >> 4;          // c-slice / k-reg group
    const int lw0 = lb * 64 + lg * 16;   // global l base of wave

    const float* xbase = x + (size_t)n * C_DIM * L_DIM;

    f32x4 acc[5];
#pragma unroll
    for (int a = 0; a < 5; ++a) acc[a] = (f32x4)0.f;
    float ss = 0.f;

    for (int ch = 0; ch < 8; ++ch) {
        const int c0 = chalf * 256 + ch * 32;
        float e[8];
#pragma unroll
        for (int j = 0; j < 8; ++j)
            e[j] = xbase[(size_t)(c0 + agrp * 8 + j) * L_DIM + lw0 + arow];
#pragma unroll
        for (int j = 0; j < 8; ++j) ss += e[j] * e[j];
        U4 bh, bl;
        bh.u.x = pack2(e[0], e[1]); bh.u.y = pack2(e[2], e[3]);
        bh.u.z = pack2(e[4], e[5]); bh.u.w = pack2(e[6], e[7]);
        float r0 = e[0] - bfh_f(e[0]), r1 = e[1] - bfh_f(e[1]);
        float r2 = e[2] - bfh_f(e[2]), r3 = e[3] - bfh_f(e[3]);
        bl.u.x = pack2(r0, r1); bl.u.y = pack2(r2, r3);
        r0 = e[4] - bfh_f(e[4]); r1 = e[5] - bfh_f(e[5]);
        r2 = e[6] - bfh_f(e[6]); r3 = e[7] - bfh_f(e[7]);
        bl.u.z = pack2(r0, r1); bl.u.w = pack2(r2, r3);
        U4 ah[5], al[5];
#pragma unroll
        for (int kt = 0; kt < 5; ++kt) {
            int aoff = (kt * 16 + arow) * C_DIM + c0 + agrp * 8;
            ah[kt].u = *reinterpret_cast<const uint4*>(&wtH[aoff]);
            al[kt].u = *reinterpret_cast<const uint4*>(&wtL[aoff]);
        }
#pragma unroll
        for (int kt = 0; kt < 5; ++kt) {
            acc[kt] = __builtin_amdgcn_mfma_f32_16x16x32_bf16(ah[kt].b, bh.b, acc[kt], 0, 0, 0);
            acc[kt] = __builtin_amdgcn_mfma_f32_16x16x32_bf16(ah[kt].b, bl.b, acc[kt], 0, 0, 0);
            acc[kt] = __builtin_amdgcn_mfma_f32_16x16x32_bf16(al[kt].b, bh.b, acc[kt], 0, 0, 0);
        }
    }

    // ---- cross-half combine through LDS (scalar layout, stride-1 = conflict-free)
    if (chalf == 1) {
#pragma unroll
        for (int kt = 0; kt < 5; ++kt)
#pragma unroll
            for (int r = 0; r < 4; ++r)
                accbuf[lg][kt][r][lane] = acc[kt][r];
        ssbuf[lg][lane] = ss;
    }
    __syncthreads();
    if (chalf == 1) return;
#pragma unroll
    for (int kt = 0; kt < 5; ++kt)
#pragma unroll
        for (int r = 0; r < 4; ++r)
            acc[kt][r] += accbuf[lg][kt][r][lane];
    ss += ssbuf[lg][lane];

    // ---- per-l inverse norm: reduce over the 4 agrp lanes
    ss += __shfl_xor(ss, 16, 64); ss += __shfl_xor(ss, 32, 64);
    const float inv = 1.0f / fmaxf(sqrtf(ss), 1e-12f);

    // ---- bias
    float4 wbv[5];
#pragma unroll
    for (int kt = 0; kt < 5; ++kt)
        wbv[kt] = *reinterpret_cast<const float4*>(&wb[kt * 16 + agrp * 4]);

    // ---- softmax per l (k spread over lanes {arow, arow+16, arow+32, arow+48})
    float aval[5][4];
    float m = -1e30f;
#pragma unroll
    for (int kt = 0; kt < 5; ++kt)
#pragma unroll
        for (int r = 0; r < 4; ++r) {
            float lg2 = acc[kt][r] * inv + ((const float*)&wbv[kt])[r];
            aval[kt][r] = lg2;
            m = fmaxf(m, lg2);
        }
    m = fmaxf(m, __shfl_xor(m, 16, 64));
    m = fmaxf(m, __shfl_xor(m, 32, 64));
    float s = 0.f;
#pragma unroll
    for (int kt = 0; kt < 5; ++kt)
#pragma unroll
        for (int r = 0; r < 4; ++r) {
            float ev = __expf(aval[kt][r] - m);
            aval[kt][r] = ev;
            s += ev;
        }
    s += __shfl_xor(s, 16, 64);
    s += __shfl_xor(s, 32, 64);
    const float rs = 1.0f / s;

    // ---- a_sum partials (sum over this wave's 16 l) + a' = a*inv as split bf16
#pragma unroll
    for (int kt = 0; kt < 4; ++kt)
#pragma unroll
        for (int r = 0; r < 4; ++r) {
            int k = kt * 16 + agrp * 4 + r;
            float a = aval[kt][r] * rs;
            float s01 = a;
#pragma unroll
            for (int off = 8; off; off >>= 1) s01 += __shfl_xor(s01, off, 64);
            if ((lane & 15) == 0)
                asum_part[((n * 16 + lb) * 4 + lg) * KK + k] = s01;
            float ap = a * inv;
            unsigned h = bfh(ap);
            float res = ap - __uint_as_float(h << 16);
            int idx = (n * KK + k) * L_DIM + lw0 + arow;
            aPh[idx] = (unsigned short)h;
            aPl[idx] = (unsigned short)bfh(res);
        }
}

// ---------------- Stage 2: weighted = a' x^T, LDS-staged MFMA GEMM + XCD swizzle -----
// Grid 512 (flat), block 256 = 4 waves; wave owns 16 c, all 4 k-tiles.
#define S2P 72   // LDS row pitch in shorts (144 B, 16B-aligned rows)
__global__ __launch_bounds__(256) void k_s2(
    const float* __restrict__ x, const unsigned short* __restrict__ aPh,
    const unsigned short* __restrict__ aPl, float* __restrict__ weighted)
{
    __shared__ unsigned short Ah[64 * S2P], Al[64 * S2P];   // aP chunk [k][l]
    __shared__ unsigned short Bh[64 * S2P], Bl[64 * S2P];   // x  chunk [c][l]

    const int flat = blockIdx.x;
    const int cq = flat >> 6;                               // 0..7
    const int n  = ((flat & 7) << 3) | ((flat >> 3) & 7);   // bijective, XCD-pinned
    const int t = threadIdx.x, lane = t & 63, w = t >> 6;
    const int arow = lane & 15, agrp = lane >> 4;

    f32x4 acc[4];
#pragma unroll
    for (int a = 0; a < 4; ++a) acc[a] = (f32x4)0.f;

    for (int step = 0; step < 16; ++step) {
        const int l0 = step * 64;
        __syncthreads();   // previous iter's reads done before restage
        // ---- stage aP [64k][64l] hi+lo: 2 uint4 per thread per buffer, coalesced
#pragma unroll
        for (int p = 0; p < 2; ++p) {
            int idx = p * 256 + t;          // 0..511 (512 uint4 = 4096 shorts)
            int k = idx >> 3;               // 8 uint4 per 64-short row
            int lc = (idx & 7) * 8;
            size_t g = (size_t)(n * KK + k) * L_DIM + l0 + lc;
            *reinterpret_cast<uint4*>(&Ah[k * S2P + lc]) = *reinterpret_cast<const uint4*>(&aPh[g]);
            *reinterpret_cast<uint4*>(&Al[k * S2P + lc]) = *reinterpret_cast<const uint4*>(&aPl[g]);
        }
        // ---- stage x [64c][64l], split-convert to bf16 hi/lo at stage time
#pragma unroll
        for (int p = 0; p < 4; ++p) {
            int idx = p * 256 + t;          // 0..1023 (1024 float4)
            int c = idx >> 4;               // 16 float4 per 64-float row
            int lc = (idx & 15) * 4;
            float4 v = *reinterpret_cast<const float4*>(
                &x[((size_t)n * C_DIM + cq * 64 + c) * L_DIM + l0 + lc]);
            uint2 hw, lw;
            hw.x = pack2(v.x, v.y); hw.y = pack2(v.z, v.w);
            float r0 = v.x - bfh_f(v.x), r1 = v.y - bfh_f(v.y);
            float r2 = v.z - bfh_f(v.z), r3 = v.w - bfh_f(v.w);
            lw.x = pack2(r0, r1); lw.y = pack2(r2, r3);
            *reinterpret_cast<uint2*>(&Bh[c * S2P + lc]) = hw;
            *reinterpret_cast<uint2*>(&Bl[c * S2P + lc]) = lw;
        }
        __syncthreads();
        // ---- compute: 2 K=32 sub-steps
#pragma unroll
        for (int ks = 0; ks < 2; ++ks) {
            const int koff = ks * 32 + agrp * 8;
            U4 bh, bl;
            bh.u = *reinterpret_cast<const uint4*>(&Bh[(w * 16 + arow) * S2P + koff]);
            bl.u = *reinterpret_cast<const uint4*>(&Bl[(w * 16 + arow) * S2P + koff]);
#pragma unroll
            for (int kt = 0; kt < 4; ++kt) {
                U4 ah, al;
                ah.u = *reinterpret_cast<const uint4*>(&Ah[(kt * 16 + arow) * S2P + koff]);
                al.u = *reinterpret_cast<const uint4*>(&Al[(kt * 16 + arow) * S2P + koff]);
                acc[kt] = __builtin_amdgcn_mfma_f32_16x16x32_bf16(ah.b, bh.b, acc[kt], 0, 0, 0);
                acc[kt] = __builtin_amdgcn_mfma_f32_16x16x32_bf16(ah.b, bl.b, acc[kt], 0, 0, 0);
                acc[kt] = __builtin_amdgcn_mfma_f32_16x16x32_bf16(al.b, bh.b, acc[kt], 0, 0, 0);
            }
        }
    }
#pragma unroll
    for (int kt = 0; kt < 4; ++kt)
#pragma unroll
        for (int r = 0; r < 4; ++r) {
            int k = kt * 16 + agrp * 4 + r;
            weighted[((size_t)n * KK + k) * C_DIM + cq * 64 + w * 16 + arow] = acc[kt][r];
        }
}

// ---------------- per-(n,k): a_sum + row sumsq of vlad ----------------
__global__ void k_rownorm(const float* __restrict__ weighted, const float* __restrict__ part,
                          const float* __restrict__ cent, float* __restrict__ a_sum,
                          float* __restrict__ rn)
{
    int nk = blockIdx.x;          // 0..4095
    int n = nk >> 6, k = nk & 63;
    int t = threadIdx.x;          // 256
    float as = 0.f;
#pragma unroll
    for (int p = 0; p < 64; ++p) as += part[(n * 64 + p) * KK + k];
    if (t == 0) a_sum[nk] = as;
    float s = 0.f;
    for (int c = t; c < C_DIM; c += 256) {
        float v = weighted[(size_t)nk * C_DIM + c] - as * cent[k * C_DIM + c];
        s += v * v;
    }
#pragma unroll
    for (int off = 32; off; off >>= 1) s += __shfl_down(s, off, 64);
    __shared__ float red[4];
    if ((t & 63) == 0) red[t >> 6] = s;
    __syncthreads();
    if (t == 0) rn[nk] = red[0] + red[1] + red[2] + red[3];
}

// ---------------- per-n global norm -> combined scale ----------------
__global__ void k_scale(const float* __restrict__ rn, float* __restrict__ scale)
{
    int n = blockIdx.x;
    int k = threadIdx.x;    // 64
    float s = rn[n * 64 + k];
    float nrm = sqrtf(s);
    float den = fmaxf(nrm, 1e-12f);
    float tk = nrm / den;
    float tot = tk * tk;
#pragma unroll
    for (int off = 32; off; off >>= 1) tot += __shfl_down(tot, off, 64);
    tot = __shfl(tot, 0, 64);
    float g = fmaxf(sqrtf(tot), 1e-12f);
    scale[n * 64 + k] = 1.0f / (den * g);
}

// ---------------- final output ----------------
__global__ void k_out(const float* __restrict__ weighted, const float* __restrict__ a_sum,
                      const float* __restrict__ cent, const float* __restrict__ scale,
                      float* __restrict__ out)
{
    int nk = blockIdx.x;
    int k = nk & 63;
    int t = threadIdx.x;
    float as = a_sum[nk];
    float sc = scale[nk];
    for (int c = t; c < C_DIM; c += 256) {
        float v = weighted[(size_t)nk * C_DIM + c] - as * cent[k * C_DIM + c];
        out[(size_t)nk * C_DIM + c] = v * sc;
    }
}

extern "C" void kernel_launch(void* const* d_in, const int* in_sizes, int n_in,
                              void* d_out, int out_size, void* d_ws, size_t ws_size,
                              hipStream_t stream)
{
    const float* x    = (const float*)d_in[0];
    const float* cent = (const float*)d_in[1];
    const float* cw   = (const float*)d_in[2];
    const float* cb   = (const float*)d_in[3];
    float* out = (float*)d_out;
    char* ws = (char*)d_ws;

    unsigned short* wtH = (unsigned short*)(ws + 0);                // 80 KB
    unsigned short* wtL = (unsigned short*)(ws + 131072);           // 80 KB
    float*          wb  = (float*)(ws + 262144);                    // 320 B
    unsigned short* aPh = (unsigned short*)(ws + 524288);           // 8 MB
    unsigned short* aPl = (unsigned short*)(ws + 8912896);          // 8 MB
    float* asum_part    = (float*)(ws + 17301504);                  // 1 MB (64 partials/nk)
    float* a_sum        = (float*)(ws + 18350080);                  // 16 KB
    float* weighted     = (float*)(ws + 18874368);                  // 8 MB
    float* rn           = (float*)(ws + 35651584);
    float* scale        = (float*)(ws + 35667968);

    k_prep<<<KP, 256, 0, stream>>>(cw, cb, wtH, wtL, wb);
    k_s1<<<dim3(16, 64), 512, 0, stream>>>(x, wtH, wtL, wb, aPh, aPl, asum_part);
    k_s2<<<512, 256, 0, stream>>>(x, aPh, aPl, weighted);
    k_rownorm<<<4096, 256, 0, stream>>>(weighted, asum_part, cent, a_sum, rn);
    k_scale<<<64, 64, 0, stream>>>(rn, scale);
    k_out<<<4096, 256, 0, stream>>>(weighted, a_sum, cent, scale, out);
}

// Round 14
// 78.450 us; speedup vs baseline: 1.9221x; 1.9221x over previous
//
#include <hip/hip_runtime.h>
#include <hip/hip_bf16.h>

#define C_DIM 512
#define L_DIM 1024
#define KK 64
#define KG 65
#define KP 80   // padded k rows (5 tiles of 16)

using f32x4  = __attribute__((ext_vector_type(4))) float;
using bf16x8 = __attribute__((ext_vector_type(8))) short;

union U4 { uint4 u; bf16x8 b; };

__device__ __forceinline__ unsigned bfh(float x) { return __float_as_uint(x) >> 16; }
__device__ __forceinline__ float bfh_f(float x) { return __uint_as_float(__float_as_uint(x) & 0xFFFF0000u); }

// pack two fp32 -> word of 2 bf16 (truncation): low16 = a, high16 = b
__device__ __forceinline__ unsigned pack2(float a, float b) {
    return __builtin_amdgcn_perm(__float_as_uint(b), __float_as_uint(a), 0x07060302u);
}

// ---------------- prep: split conv_w into bf16 hi/lo IN MFMA FRAGMENT ORDER ----------
// wp[((ch*5 + kt)*64 + lane)*8 + j] = w[kt*16 + (lane&15)][ch*32 + (lane>>4)*8 + j]
// so stage-1 A-fragment loads are lane-consecutive (1 KB contiguous per instruction)
// instead of 64-way scattered gathers (the measured s1 bottleneck).
__global__ void k_prep(const float* __restrict__ conv_w, const float* __restrict__ conv_b,
                       unsigned short* __restrict__ wpH, unsigned short* __restrict__ wpL,
                       float* __restrict__ wb)
{
    int ch = blockIdx.x;          // 0..15
    int kt = blockIdx.y;          // 0..4
    int t  = threadIdx.x;         // 0..255
    for (int p = 0; p < 2; ++p) {
        int idx = p * 256 + t;    // 0..511
        int lane = idx >> 3, j = idx & 7;
        int k = kt * 16 + (lane & 15);
        int c = ch * 32 + (lane >> 4) * 8 + j;
        float v = (k < KG) ? conv_w[k * C_DIM + c] : 0.f;
        unsigned h = bfh(v);
        float r = v - __uint_as_float(h << 16);
        int pos = ((ch * 5 + kt) << 9) + idx;
        wpH[pos] = (unsigned short)h;
        wpL[pos] = (unsigned short)bfh(r);
    }
    if (ch == 0 && kt == 0 && t < KP) wb[t] = (t < KG) ? conv_b[t] : -1e30f;
}

// ---------------- Stage 1: register-direct MFMA logits, packed weights ----------------
// Grid (8 lb, 64 n), block 256 = 4 waves. Wave owns 32 l (2 tiles of 16), all 5 k-tiles.
// B-fragments gathered from global x (4x64B segments/instr); A-fragments are now
// CONTIGUOUS packed loads (8x128B lines/instr, 8x fewer memory transactions).
__global__ __launch_bounds__(256) void k_s1(
    const float* __restrict__ x, const unsigned short* __restrict__ wpH,
    const unsigned short* __restrict__ wpL, const float* __restrict__ wb,
    unsigned short* __restrict__ aPh, unsigned short* __restrict__ aPl,
    float* __restrict__ asum_part)
{
    const int lb = blockIdx.x, n = blockIdx.y;
    const int t = threadIdx.x, lane = t & 63, w = t >> 6;
    const int arow = lane & 15;          // A/C row & B col within tile
    const int agrp = lane >> 4;          // k-slice group
    const int lw0 = lb * 128 + w * 32;   // global l base of wave

    const float* xbase = x + (size_t)n * C_DIM * L_DIM;

    f32x4 acc[5][2];
#pragma unroll
    for (int a = 0; a < 5; ++a)
#pragma unroll
        for (int b = 0; b < 2; ++b) acc[a][b] = (f32x4)0.f;
    float ss0 = 0.f, ss1 = 0.f;

    for (int ch = 0; ch < 16; ++ch) {
        const int c0 = ch * 32;
        float e0[8], e1[8];
#pragma unroll
        for (int j = 0; j < 8; ++j) {
            const float* col = &xbase[(size_t)(c0 + agrp * 8 + j) * L_DIM + lw0 + arow];
            e0[j] = col[0];
            e1[j] = col[16];
        }
#pragma unroll
        for (int j = 0; j < 8; ++j) { ss0 += e0[j] * e0[j]; ss1 += e1[j] * e1[j]; }
        U4 bh[2], bl[2];
        bh[0].u.x = pack2(e0[0], e0[1]); bh[0].u.y = pack2(e0[2], e0[3]);
        bh[0].u.z = pack2(e0[4], e0[5]); bh[0].u.w = pack2(e0[6], e0[7]);
        bh[1].u.x = pack2(e1[0], e1[1]); bh[1].u.y = pack2(e1[2], e1[3]);
        bh[1].u.z = pack2(e1[4], e1[5]); bh[1].u.w = pack2(e1[6], e1[7]);
        float r0, r1, r2, r3;
        r0 = e0[0] - bfh_f(e0[0]); r1 = e0[1] - bfh_f(e0[1]);
        r2 = e0[2] - bfh_f(e0[2]); r3 = e0[3] - bfh_f(e0[3]);
        bl[0].u.x = pack2(r0, r1); bl[0].u.y = pack2(r2, r3);
        r0 = e0[4] - bfh_f(e0[4]); r1 = e0[5] - bfh_f(e0[5]);
        r2 = e0[6] - bfh_f(e0[6]); r3 = e0[7] - bfh_f(e0[7]);
        bl[0].u.z = pack2(r0, r1); bl[0].u.w = pack2(r2, r3);
        r0 = e1[0] - bfh_f(e1[0]); r1 = e1[1] - bfh_f(e1[1]);
        r2 = e1[2] - bfh_f(e1[2]); r3 = e1[3] - bfh_f(e1[3]);
        bl[1].u.x = pack2(r0, r1); bl[1].u.y = pack2(r2, r3);
        r0 = e1[4] - bfh_f(e1[4]); r1 = e1[5] - bfh_f(e1[5]);
        r2 = e1[6] - bfh_f(e1[6]); r3 = e1[7] - bfh_f(e1[7]);
        bl[1].u.z = pack2(r0, r1); bl[1].u.w = pack2(r2, r3);
        // ---- A fragments: packed, lane-consecutive (contiguous 1 KB per instr)
        U4 ah[5], al[5];
#pragma unroll
        for (int kt = 0; kt < 5; ++kt) {
            int poff = (((ch * 5 + kt) << 6) + lane) << 3;
            ah[kt].u = *reinterpret_cast<const uint4*>(&wpH[poff]);
            al[kt].u = *reinterpret_cast<const uint4*>(&wpL[poff]);
        }
#pragma unroll
        for (int kt = 0; kt < 5; ++kt)
#pragma unroll
            for (int lt = 0; lt < 2; ++lt) {
                acc[kt][lt] = __builtin_amdgcn_mfma_f32_16x16x32_bf16(ah[kt].b, bh[lt].b, acc[kt][lt], 0, 0, 0);
                acc[kt][lt] = __builtin_amdgcn_mfma_f32_16x16x32_bf16(ah[kt].b, bl[lt].b, acc[kt][lt], 0, 0, 0);
                acc[kt][lt] = __builtin_amdgcn_mfma_f32_16x16x32_bf16(al[kt].b, bh[lt].b, acc[kt][lt], 0, 0, 0);
            }
    }

    ss0 += __shfl_xor(ss0, 16, 64); ss0 += __shfl_xor(ss0, 32, 64);
    ss1 += __shfl_xor(ss1, 16, 64); ss1 += __shfl_xor(ss1, 32, 64);
    float invc[2];
    invc[0] = 1.0f / fmaxf(sqrtf(ss0), 1e-12f);
    invc[1] = 1.0f / fmaxf(sqrtf(ss1), 1e-12f);

    float4 wbv[5];
#pragma unroll
    for (int kt = 0; kt < 5; ++kt)
        wbv[kt] = *reinterpret_cast<const float4*>(&wb[kt * 16 + agrp * 4]);

    float aval[5][2][4];
    float rs[2];
#pragma unroll
    for (int lt = 0; lt < 2; ++lt) {
        float m = -1e30f;
#pragma unroll
        for (int kt = 0; kt < 5; ++kt)
#pragma unroll
            for (int r = 0; r < 4; ++r) {
                float lg = acc[kt][lt][r] * invc[lt] + ((const float*)&wbv[kt])[r];
                aval[kt][lt][r] = lg;
                m = fmaxf(m, lg);
            }
        m = fmaxf(m, __shfl_xor(m, 16, 64));
        m = fmaxf(m, __shfl_xor(m, 32, 64));
        float s = 0.f;
#pragma unroll
        for (int kt = 0; kt < 5; ++kt)
#pragma unroll
            for (int r = 0; r < 4; ++r) {
                float e = __expf(aval[kt][lt][r] - m);
                aval[kt][lt][r] = e;
                s += e;
            }
        s += __shfl_xor(s, 16, 64);
        s += __shfl_xor(s, 32, 64);
        rs[lt] = 1.0f / s;
    }

#pragma unroll
    for (int kt = 0; kt < 4; ++kt)
#pragma unroll
        for (int r = 0; r < 4; ++r) {
            int k = kt * 16 + agrp * 4 + r;
            float s01 = 0.f;
#pragma unroll
            for (int lt = 0; lt < 2; ++lt) {
                float a = aval[kt][lt][r] * rs[lt];
                aval[kt][lt][r] = a;
                s01 += a;
            }
#pragma unroll
            for (int off = 8; off; off >>= 1) s01 += __shfl_xor(s01, off, 64);
            if ((lane & 15) == 0)
                asum_part[((n * 8 + lb) * 4 + w) * KK + k] = s01;
#pragma unroll
            for (int lt = 0; lt < 2; ++lt) {
                float ap = aval[kt][lt][r] * invc[lt];
                unsigned h = bfh(ap);
                float res = ap - __uint_as_float(h << 16);
                int idx = (n * KK + k) * L_DIM + lw0 + lt * 16 + arow;
                aPh[idx] = (unsigned short)h;
                aPl[idx] = (unsigned short)bfh(res);
            }
        }
}

// ---------------- Stage 2: weighted = a' x^T, LDS-staged MFMA GEMM + XCD swizzle -----
// Grid 512 (flat), block 256 = 4 waves; wave owns 16 c, all 4 k-tiles.
#define S2P 72   // LDS row pitch in shorts (144 B, 16B-aligned rows)
__global__ __launch_bounds__(256) void k_s2(
    const float* __restrict__ x, const unsigned short* __restrict__ aPh,
    const unsigned short* __restrict__ aPl, float* __restrict__ weighted)
{
    __shared__ unsigned short Ah[64 * S2P], Al[64 * S2P];   // aP chunk [k][l]
    __shared__ unsigned short Bh[64 * S2P], Bl[64 * S2P];   // x  chunk [c][l]

    const int flat = blockIdx.x;
    const int cq = flat >> 6;                               // 0..7
    const int n  = ((flat & 7) << 3) | ((flat >> 3) & 7);   // bijective, XCD-pinned
    const int t = threadIdx.x, lane = t & 63, w = t >> 6;
    const int arow = lane & 15, agrp = lane >> 4;

    f32x4 acc[4];
#pragma unroll
    for (int a = 0; a < 4; ++a) acc[a] = (f32x4)0.f;

    for (int step = 0; step < 16; ++step) {
        const int l0 = step * 64;
        __syncthreads();   // previous iter's reads done before restage
        // ---- stage aP [64k][64l] hi+lo: 2 uint4 per thread per buffer, coalesced
#pragma unroll
        for (int p = 0; p < 2; ++p) {
            int idx = p * 256 + t;          // 0..511 (512 uint4 = 4096 shorts)
            int k = idx >> 3;               // 8 uint4 per 64-short row
            int lc = (idx & 7) * 8;
            size_t g = (size_t)(n * KK + k) * L_DIM + l0 + lc;
            *reinterpret_cast<uint4*>(&Ah[k * S2P + lc]) = *reinterpret_cast<const uint4*>(&aPh[g]);
            *reinterpret_cast<uint4*>(&Al[k * S2P + lc]) = *reinterpret_cast<const uint4*>(&aPl[g]);
        }
        // ---- stage x [64c][64l], split-convert to bf16 hi/lo at stage time
#pragma unroll
        for (int p = 0; p < 4; ++p) {
            int idx = p * 256 + t;          // 0..1023 (1024 float4)
            int c = idx >> 4;               // 16 float4 per 64-float row
            int lc = (idx & 15) * 4;
            float4 v = *reinterpret_cast<const float4*>(
                &x[((size_t)n * C_DIM + cq * 64 + c) * L_DIM + l0 + lc]);
            uint2 hw, lw;
            hw.x = pack2(v.x, v.y); hw.y = pack2(v.z, v.w);
            float r0 = v.x - bfh_f(v.x), r1 = v.y - bfh_f(v.y);
            float r2 = v.z - bfh_f(v.z), r3 = v.w - bfh_f(v.w);
            lw.x = pack2(r0, r1); lw.y = pack2(r2, r3);
            *reinterpret_cast<uint2*>(&Bh[c * S2P + lc]) = hw;
            *reinterpret_cast<uint2*>(&Bl[c * S2P + lc]) = lw;
        }
        __syncthreads();
        // ---- compute: 2 K=32 sub-steps
#pragma unroll
        for (int ks = 0; ks < 2; ++ks) {
            const int koff = ks * 32 + agrp * 8;
            U4 bh, bl;
            bh.u = *reinterpret_cast<const uint4*>(&Bh[(w * 16 + arow) * S2P + koff]);
            bl.u = *reinterpret_cast<const uint4*>(&Bl[(w * 16 + arow) * S2P + koff]);
#pragma unroll
            for (int kt = 0; kt < 4; ++kt) {
                U4 ah, al;
                ah.u = *reinterpret_cast<const uint4*>(&Ah[(kt * 16 + arow) * S2P + koff]);
                al.u = *reinterpret_cast<const uint4*>(&Al[(kt * 16 + arow) * S2P + koff]);
                acc[kt] = __builtin_amdgcn_mfma_f32_16x16x32_bf16(ah.b, bh.b, acc[kt], 0, 0, 0);
                acc[kt] = __builtin_amdgcn_mfma_f32_16x16x32_bf16(ah.b, bl.b, acc[kt], 0, 0, 0);
                acc[kt] = __builtin_amdgcn_mfma_f32_16x16x32_bf16(al.b, bh.b, acc[kt], 0, 0, 0);
            }
        }
    }
#pragma unroll
    for (int kt = 0; kt < 4; ++kt)
#pragma unroll
        for (int r = 0; r < 4; ++r) {
            int k = kt * 16 + agrp * 4 + r;
            weighted[((size_t)n * KK + k) * C_DIM + cq * 64 + w * 16 + arow] = acc[kt][r];
        }
}

// ---------------- per-(n,k): a_sum + row sumsq of vlad ----------------
__global__ void k_rownorm(const float* __restrict__ weighted, const float* __restrict__ part,
                          const float* __restrict__ cent, float* __restrict__ a_sum,
                          float* __restrict__ rn)
{
    int nk = blockIdx.x;          // 0..4095
    int n = nk >> 6, k = nk & 63;
    int t = threadIdx.x;          // 256
    float as = 0.f;
#pragma unroll
    for (int p = 0; p < 32; ++p) as += part[(n * 32 + p) * KK + k];
    if (t == 0) a_sum[nk] = as;
    float s = 0.f;
    for (int c = t; c < C_DIM; c += 256) {
        float v = weighted[(size_t)nk * C_DIM + c] - as * cent[k * C_DIM + c];
        s += v * v;
    }
#pragma unroll
    for (int off = 32; off; off >>= 1) s += __shfl_down(s, off, 64);
    __shared__ float red[4];
    if ((t & 63) == 0) red[t >> 6] = s;
    __syncthreads();
    if (t == 0) rn[nk] = red[0] + red[1] + red[2] + red[3];
}

// ---------------- per-n global norm -> combined scale ----------------
__global__ void k_scale(const float* __restrict__ rn, float* __restrict__ scale)
{
    int n = blockIdx.x;
    int k = threadIdx.x;    // 64
    float s = rn[n * 64 + k];
    float nrm = sqrtf(s);
    float den = fmaxf(nrm, 1e-12f);
    float tk = nrm / den;
    float tot = tk * tk;
#pragma unroll
    for (int off = 32; off; off >>= 1) tot += __shfl_down(tot, off, 64);
    tot = __shfl(tot, 0, 64);
    float g = fmaxf(sqrtf(tot), 1e-12f);
    scale[n * 64 + k] = 1.0f / (den * g);
}

// ---------------- final output ----------------
__global__ void k_out(const float* __restrict__ weighted, const float* __restrict__ a_sum,
                      const float* __restrict__ cent, const float* __restrict__ scale,
                      float* __restrict__ out)
{
    int nk = blockIdx.x;
    int k = nk & 63;
    int t = threadIdx.x;
    float as = a_sum[nk];
    float sc = scale[nk];
    for (int c = t; c < C_DIM; c += 256) {
        float v = weighted[(size_t)nk * C_DIM + c] - as * cent[k * C_DIM + c];
        out[(size_t)nk * C_DIM + c] = v * sc;
    }
}

extern "C" void kernel_launch(void* const* d_in, const int* in_sizes, int n_in,
                              void* d_out, int out_size, void* d_ws, size_t ws_size,
                              hipStream_t stream)
{
    const float* x    = (const float*)d_in[0];
    const float* cent = (const float*)d_in[1];
    const float* cw   = (const float*)d_in[2];
    const float* cb   = (const float*)d_in[3];
    float* out = (float*)d_out;
    char* ws = (char*)d_ws;

    unsigned short* wpH = (unsigned short*)(ws + 0);                // 80 KB packed
    unsigned short* wpL = (unsigned short*)(ws + 131072);           // 80 KB packed
    float*          wb  = (float*)(ws + 262144);                    // 320 B
    unsigned short* aPh = (unsigned short*)(ws + 524288);           // 8 MB
    unsigned short* aPl = (unsigned short*)(ws + 8912896);          // 8 MB
    float* asum_part    = (float*)(ws + 17301504);                  // 512 KB
    float* a_sum        = (float*)(ws + 17825792);                  // 16 KB
    float* weighted     = (float*)(ws + 18874368);                  // 8 MB
    float* rn           = (float*)(ws + 35651584);
    float* scale        = (float*)(ws + 35667968);

    k_prep<<<dim3(16, 5), 256, 0, stream>>>(cw, cb, wpH, wpL, wb);
    k_s1<<<dim3(8, 64), 256, 0, stream>>>(x, wpH, wpL, wb, aPh, aPl, asum_part);
    k_s2<<<512, 256, 0, stream>>>(x, aPh, aPl, weighted);
    k_rownorm<<<4096, 256, 0, stream>>>(weighted, asum_part, cent, a_sum, rn);
    k_scale<<<64, 64, 0, stream>>>(rn, scale);
    k_out<<<4096, 256, 0, stream>>>(weighted, a_sum, cent, scale, out);
}